// Round 7
// baseline (316.623 us; speedup 1.0000x reference)
//
#include <hip/hip_runtime.h>

#define S_LEN 4096

typedef __attribute__((ext_vector_type(4)))  float f32x4;
typedef __attribute__((ext_vector_type(16))) float f32x16;
typedef __attribute__((ext_vector_type(8)))  short bf16x8;
typedef __attribute__((ext_vector_type(4)))  short bf16x4;
typedef __attribute__((ext_vector_type(4)))  unsigned short us4;

static __device__ __forceinline__ unsigned short f2bf(float f) {
    unsigned u = __float_as_uint(f);
    return (unsigned short)((u + 0x7fffu + ((u >> 16) & 1u)) >> 16);
}

static __device__ __forceinline__ float fast_exp2(float x) {
#if __has_builtin(__builtin_amdgcn_exp2f)
    return __builtin_amdgcn_exp2f(x);
#else
    return exp2f(x);
#endif
}

// ---------------------------------------------------------------------------
// Kernel 1: projections. Q = (x|g)@Wq * 0.25*log2(e)  -> bf16 [bh][S][16]
//           K = (x|g)@Wk                              -> bf16 [bh][S][16]
//           V =  x  @Wv  (transposed via LDS)         -> bf16 [bh][16][S]
// 32 tokens / block, 256 threads (4 waves). lane = output column (h*16+d).
// Q and K are separate passes so only 80 weight VGPRs are live at a time.
// ---------------------------------------------------------------------------
__global__ __launch_bounds__(256) void ga_proj(
    const float* __restrict__ x, const float* __restrict__ gene,
    const float* __restrict__ Wq, const float* __restrict__ Wk,
    const float* __restrict__ Wv,
    unsigned short* __restrict__ Qw, unsigned short* __restrict__ Kw,
    unsigned short* __restrict__ VTw)
{
    __shared__ float xid[32][84];   // 80 used, pad to 84 for float4 alignment
    __shared__ float vtl[64][33];
    const int tid = threadIdx.x;
    const int tbase = blockIdx.x * 32;

    // stage x: 32*64 floats
    #pragma unroll
    for (int r = 0; r < 8; ++r) {
        int idx = tid + r * 256;
        int t = idx >> 6, i = idx & 63;
        xid[t][i] = x[(size_t)(tbase + t) * 64 + i];
    }
    // stage gene: 32*16 floats
    #pragma unroll
    for (int r = 0; r < 2; ++r) {
        int idx = tid + r * 256;
        int t = idx >> 4, i = idx & 15;
        xid[t][64 + i] = gene[(size_t)(tbase + t) * 16 + i];
    }
    __syncthreads();

    const int lane = tid & 63;
    const int wave = tid >> 6;
    const int b = tbase >> 12;        // token/4096
    const int s0 = tbase & 4095;
    const int h = lane >> 4, d = lane & 15;
    const size_t obase = ((size_t)(b*4 + h) * S_LEN) * 16 + d;

    // ---- Q pass ----
    {
        float wq[80];
        #pragma unroll
        for (int i = 0; i < 80; ++i) wq[i] = Wq[i*64 + lane];
        for (int tt = 0; tt < 8; ++tt) {
            int t = wave * 8 + tt;
            float aq = 0.f;
            #pragma unroll
            for (int i4 = 0; i4 < 20; ++i4) {
                float4 xv = *(const float4*)&xid[t][i4 * 4];
                aq += xv.x * wq[i4*4+0] + xv.y * wq[i4*4+1]
                    + xv.z * wq[i4*4+2] + xv.w * wq[i4*4+3];
            }
            Qw[obase + (size_t)(s0 + t) * 16] = f2bf(aq * 0.36067376022224085f); // 0.25*log2(e)
        }
    }
    // ---- K pass ----
    {
        float wk[80];
        #pragma unroll
        for (int i = 0; i < 80; ++i) wk[i] = Wk[i*64 + lane];
        for (int tt = 0; tt < 8; ++tt) {
            int t = wave * 8 + tt;
            float ak = 0.f;
            #pragma unroll
            for (int i4 = 0; i4 < 20; ++i4) {
                float4 xv = *(const float4*)&xid[t][i4 * 4];
                ak += xv.x * wk[i4*4+0] + xv.y * wk[i4*4+1]
                    + xv.z * wk[i4*4+2] + xv.w * wk[i4*4+3];
            }
            Kw[obase + (size_t)(s0 + t) * 16] = f2bf(ak);
        }
    }
    // ---- V pass (into LDS for transpose) ----
    {
        float wv[64];
        #pragma unroll
        for (int i = 0; i < 64; ++i) wv[i] = Wv[i*64 + lane];
        for (int tt = 0; tt < 8; ++tt) {
            int t = wave * 8 + tt;
            float av = 0.f;
            #pragma unroll
            for (int i4 = 0; i4 < 16; ++i4) {
                float4 xv = *(const float4*)&xid[t][i4 * 4];
                av += xv.x * wv[i4*4+0] + xv.y * wv[i4*4+1]
                    + xv.z * wv[i4*4+2] + xv.w * wv[i4*4+3];
            }
            vtl[lane][t] = av;
        }
    }
    __syncthreads();
    // write V^T: row = out-col (h*16+d), 8 s-positions per thread
    {
        int row = tid >> 2, c0 = (tid & 3) * 8;
        int vh = row >> 4, vd = row & 15;
        size_t o = ((size_t)(b*4 + vh) * 16 + vd) * S_LEN + s0 + c0;
        us4 lo = { f2bf(vtl[row][c0+0]), f2bf(vtl[row][c0+1]),
                   f2bf(vtl[row][c0+2]), f2bf(vtl[row][c0+3]) };
        us4 hi4 = { f2bf(vtl[row][c0+4]), f2bf(vtl[row][c0+5]),
                    f2bf(vtl[row][c0+6]), f2bf(vtl[row][c0+7]) };
        *(us4*)(VTw + o) = lo;
        *(us4*)(VTw + o + 4) = hi4;
    }
}

// ---------------------------------------------------------------------------
// Kernel 2: flash attention, no max-subtraction (logits bounded ~|3|).
// Block = 4 waves; each wave owns one 32-row q tile of one (b,h).
// Per 32-k tile: S = mfma_32x32x16(A=K, B=Q)  (lane: q=lane&31, k'=C-row)
//   p = exp2(S); denom += p; P -> private LDS (bf16) ; then
//   acc_{0,1} = mfma_16x16x32(A=P^T half, B=V) accumulated over k tiles.
// ---------------------------------------------------------------------------
__global__ __launch_bounds__(256) void ga_attn(
    const unsigned short* __restrict__ Qw, const unsigned short* __restrict__ Kw,
    const unsigned short* __restrict__ VTw, float* __restrict__ Ow)
{
    __shared__ __align__(16) unsigned short Pl[4][2][32][44]; // dbuf, 44-stride
    __shared__ float dnl[4][32];

    const int tid = threadIdx.x;
    const int lane = tid & 63;
    const int wave = tid >> 6;
    const int bh = blockIdx.x >> 5;                 // 0..15
    const int qt = (blockIdx.x & 31) * 4 + wave;    // 0..127
    const int qbase = qt * 32;
    const int lq = lane & 31, hi = lane >> 5;

    const size_t head = (size_t)bh * S_LEN * 16;
    const bf16x8 qf = *(const bf16x8*)(Qw + head + (size_t)(qbase + lq) * 16 + hi * 8);
    const unsigned short* kp = Kw + head + (size_t)lq * 16 + hi * 8;
    const unsigned short* vp = VTw + head + (size_t)(lane & 15) * S_LEN + (lane >> 4) * 8;
    unsigned short* pw = &Pl[wave][0][lq][4 * hi];
    const unsigned short* pr0 = &Pl[wave][0][lane & 15][(lane >> 4) * 8];
    const unsigned short* pr1 = pr0 + 16 * 44;

    const f32x16 zero16 = {};
    f32x4 acc0 = {}, acc1 = {};
    float denomA = 0.f, denomB = 0.f;

    bf16x8 kf = *(const bf16x8*)(kp);
    bf16x8 vf = *(const bf16x8*)(vp);

    for (int kt = 0; kt < 128; ++kt) {
        f32x16 sv = __builtin_amdgcn_mfma_f32_32x32x16_bf16(kf, qf, zero16, 0, 0, 0);
        bf16x8 vc = vf;
        // prefetch next tile (clamped; issued before the LDS fence)
        const int ktn = (kt + 1) & 127;
        kf = *(const bf16x8*)(kp + (size_t)ktn * 512);
        vf = *(const bf16x8*)(vp + (size_t)ktn * 32);

        const int boff = (kt & 1) * (32 * 44);
        #pragma unroll
        for (int g = 0; g < 4; ++g) {
            float p0 = fast_exp2(sv[4*g+0]);
            float p1 = fast_exp2(sv[4*g+1]);
            float p2 = fast_exp2(sv[4*g+2]);
            float p3 = fast_exp2(sv[4*g+3]);
            if (g & 1) denomB += (p0 + p1) + (p2 + p3);
            else       denomA += (p0 + p1) + (p2 + p3);
            us4 pk = { f2bf(p0), f2bf(p1), f2bf(p2), f2bf(p3) };
            *(us4*)(pw + boff + 8 * g) = pk;   // rows k' = 8g+4hi .. +3, col q=lq
        }
        asm volatile("s_waitcnt lgkmcnt(0)" ::: "memory");

        bf16x4 a0l = *(const bf16x4*)(pr0 + boff);
        bf16x4 a0h = *(const bf16x4*)(pr0 + boff + 4);
        bf16x4 a1l = *(const bf16x4*)(pr1 + boff);
        bf16x4 a1h = *(const bf16x4*)(pr1 + boff + 4);
        bf16x8 a0 = __builtin_shufflevector(a0l, a0h, 0,1,2,3,4,5,6,7);
        bf16x8 a1 = __builtin_shufflevector(a1l, a1h, 0,1,2,3,4,5,6,7);
        acc0 = __builtin_amdgcn_mfma_f32_16x16x32_bf16(a0, vc, acc0, 0, 0, 0);
        acc1 = __builtin_amdgcn_mfma_f32_16x16x32_bf16(a1, vc, acc1, 0, 0, 0);
    }

    float denom = denomA + denomB;
    denom += __shfl_xor(denom, 32);
    if (lane < 32) dnl[wave][lane] = denom;
    asm volatile("s_waitcnt lgkmcnt(0)" ::: "memory");

    const int b = bh >> 2, h = bh & 3;
    const int d = lane & 15;
    const int qr = (lane >> 4) * 4;
    float* op = Ow + ((size_t)b * S_LEN + qbase) * 64 + h * 16 + d;
    #pragma unroll
    for (int r = 0; r < 4; ++r) {
        float dn0 = dnl[wave][qr + r];
        float dn1 = dnl[wave][qr + r + 16];
        op[(size_t)(qr + r) * 64]      = acc0[r] / dn0;
        op[(size_t)(qr + r + 16) * 64] = acc1[r] / dn1;
    }
}

// ---------------------------------------------------------------------------
// Kernel 3: out = O @ Wo   (fp32, Wo staged in LDS)
// ---------------------------------------------------------------------------
__global__ __launch_bounds__(256) void ga_wo(
    const float* __restrict__ O, const float* __restrict__ Wo,
    float* __restrict__ out)
{
    __shared__ float wl[64][64];
    const int tid = threadIdx.x;
    #pragma unroll
    for (int r = 0; r < 16; ++r) {
        int idx = tid + r * 256;
        wl[idx >> 6][idx & 63] = Wo[idx];
    }
    __syncthreads();
    const int o = tid & 63;
    const int t = blockIdx.x * 4 + (tid >> 6);
    const float* orow = O + (size_t)t * 64;
    float acc = 0.f;
    #pragma unroll
    for (int c4 = 0; c4 < 16; ++c4) {
        float4 ov = *(const float4*)(orow + c4 * 4);
        acc += ov.x * wl[c4*4+0][o];
        acc += ov.y * wl[c4*4+1][o];
        acc += ov.z * wl[c4*4+2][o];
        acc += ov.w * wl[c4*4+3][o];
    }
    out[(size_t)t * 64 + o] = acc;
}

extern "C" void kernel_launch(void* const* d_in, const int* in_sizes, int n_in,
                              void* d_out, int out_size, void* d_ws, size_t ws_size,
                              hipStream_t stream) {
    const float* x    = (const float*)d_in[0];
    const float* gene = (const float*)d_in[1];
    const float* Wq   = (const float*)d_in[2];
    const float* Wk   = (const float*)d_in[3];
    const float* Wv   = (const float*)d_in[4];
    const float* Wo   = (const float*)d_in[5];

    unsigned short* Qw  = (unsigned short*)d_ws;                 // 2 MB
    unsigned short* Kw  = Qw + (1u << 20);                       // 2 MB
    unsigned short* VTw = Kw + (1u << 20);                       // 2 MB
    float* Ow = (float*)((char*)d_ws + 6u * (1u << 20));         // 4 MB

    ga_proj<<<512, 256, 0, stream>>>(x, gene, Wq, Wk, Wv, Qw, Kw, VTw);
    ga_attn<<<512, 256, 0, stream>>>(Qw, Kw, VTw, Ow);
    ga_wo<<<4096, 256, 0, stream>>>(Ow, Wo, (float*)d_out);
}

// Round 9
// 156.387 us; speedup vs baseline: 2.0246x; 2.0246x over previous
//
#include <hip/hip_runtime.h>

#define S_LEN 4096

typedef __attribute__((ext_vector_type(4)))  float f32x4;
typedef __attribute__((ext_vector_type(16))) float f32x16;
typedef __attribute__((ext_vector_type(8)))  short bf16x8;
typedef __attribute__((ext_vector_type(4)))  short bf16x4;
typedef __attribute__((ext_vector_type(4)))  unsigned short us4;

static __device__ __forceinline__ unsigned short f2bf(float f) {
    unsigned u = __float_as_uint(f);
    return (unsigned short)((u + 0x7fffu + ((u >> 16) & 1u)) >> 16);
}

static __device__ __forceinline__ float fast_exp2(float x) {
#if __has_builtin(__builtin_amdgcn_exp2f)
    return __builtin_amdgcn_exp2f(x);
#else
    return exp2f(x);
#endif
}

// ---------------------------------------------------------------------------
// Kernel 1 (MFMA rewrite — r7 was a 256-VGPR spill storm, 174us, 209MB scratch
// writes): projections as one GEMM [tokens x 80] @ [80 x 192] where
// W_cat = [Wq*0.25*log2e | Wk | Wv(zero-padded k=64..79)].
//   outputs: Q -> bf16 [bh][S][16], K -> bf16 [bh][S][16], V^T -> bf16 [bh][16][S]
// 128 tokens / block (4 waves x 32-token tile), 128 blocks.
// B-fragments (W^T) staged once per block in LDS in fragment-packed order
// (lane-consecutive 16B => conflict-free ds_read_b128). A-fragments built
// from global fp32 directly (each token row read exactly once).
// Same-phi A/B k-slot mapping (lane: lq=lane&31 -> m/n, hi=lane>>5 -> k-slot
// hi*8+j) — HW-validated by ga_attn passing at absmax 4.9e-4.
// ---------------------------------------------------------------------------
__global__ __launch_bounds__(256) void ga_proj(
    const float* __restrict__ x, const float* __restrict__ gene,
    const float* __restrict__ Wq, const float* __restrict__ Wk,
    const float* __restrict__ Wv,
    unsigned short* __restrict__ Qw, unsigned short* __restrict__ Kw,
    unsigned short* __restrict__ VTw)
{
    // wfrag[nt][kk][lane][j] = W_cat[kk*16 + (lane>>5)*8 + j][nt*32 + (lane&31)]
    __shared__ __align__(16) unsigned short wfrag[6][5][64][8];   // 30 KB

    const int tid = threadIdx.x;
    const int tok0 = blockIdx.x * 128;
    const int b = tok0 >> 12;          // batch (128 | 4096)
    const int s0 = tok0 & 4095;

    // ---- stage W fragments (one-time per block; reads coalesced in c) ----
    for (int idx = tid; idx < 80 * 64; idx += 256) {
        int k = idx >> 6, c = idx & 63;
        float w = Wq[idx] * 0.36067376022224085f;   // fold 0.25*log2(e)
        wfrag[c >> 5][k >> 4][(((k >> 3) & 1) << 5) | (c & 31)][k & 7] = f2bf(w);
    }
    for (int idx = tid; idx < 80 * 64; idx += 256) {
        int k = idx >> 6, c = idx & 63;
        int cg = c + 64;
        wfrag[cg >> 5][k >> 4][(((k >> 3) & 1) << 5) | (c & 31)][k & 7] = f2bf(Wk[idx]);
    }
    for (int idx = tid; idx < 64 * 64; idx += 256) {
        int k = idx >> 6, c = idx & 63;
        int cg = c + 128;
        wfrag[cg >> 5][k >> 4][(((k >> 3) & 1) << 5) | (c & 31)][k & 7] = f2bf(Wv[idx]);
    }
    // zero-pad V k-rows 64..79 (gene must not feed V): nt 4..5, kk=4
    for (int idx = tid; idx < 1024; idx += 256) {
        int nt = 4 + (idx >> 9);
        int rest = idx & 511;
        wfrag[nt][4][rest >> 3][rest & 7] = 0;
    }
    __syncthreads();

    const int lane = tid & 63;
    const int wave = tid >> 6;
    const int lq = lane & 31, hi = lane >> 5;
    const int tok = tok0 + wave * 32 + lq;     // this lane's token (A m-row)

    // ---- A fragments from global: x|gene row of `tok`, bf16 ----
    bf16x8 afrag[5];
    #pragma unroll
    for (int kk = 0; kk < 4; ++kk) {
        const float* p = x + (size_t)tok * 64 + kk * 16 + hi * 8;
        float4 l4 = *(const float4*)p;
        float4 h4 = *(const float4*)(p + 4);
        bf16x8 av;
        av[0] = (short)f2bf(l4.x); av[1] = (short)f2bf(l4.y);
        av[2] = (short)f2bf(l4.z); av[3] = (short)f2bf(l4.w);
        av[4] = (short)f2bf(h4.x); av[5] = (short)f2bf(h4.y);
        av[6] = (short)f2bf(h4.z); av[7] = (short)f2bf(h4.w);
        afrag[kk] = av;
    }
    {
        const float* p = gene + (size_t)tok * 16 + hi * 8;
        float4 l4 = *(const float4*)p;
        float4 h4 = *(const float4*)(p + 4);
        bf16x8 av;
        av[0] = (short)f2bf(l4.x); av[1] = (short)f2bf(l4.y);
        av[2] = (short)f2bf(l4.z); av[3] = (short)f2bf(l4.w);
        av[4] = (short)f2bf(h4.x); av[5] = (short)f2bf(h4.y);
        av[6] = (short)f2bf(h4.z); av[7] = (short)f2bf(h4.w);
        afrag[4] = av;
    }

    const f32x16 z16 = {};
    #pragma unroll
    for (int nt = 0; nt < 6; ++nt) {
        f32x16 acc = z16;
        #pragma unroll
        for (int kk = 0; kk < 5; ++kk) {
            bf16x8 bfr = *(const bf16x8*)&wfrag[nt][kk][lane][0];
            acc = __builtin_amdgcn_mfma_f32_32x32x16_bf16(afrag[kk], bfr, acc, 0, 0, 0);
        }
        // C layout: col n = lane&31 (out col), row m = (r&3)+8*(r>>2)+4*hi (token)
        const int c = nt * 32 + lq;
        if (nt < 2) {                       // Q cols 0..63
            int h = c >> 4, d = c & 15;
            size_t base = ((size_t)(b * 4 + h) * S_LEN) * 16 + d;
            #pragma unroll
            for (int r = 0; r < 16; ++r) {
                int m = (r & 3) + 8 * (r >> 2) + 4 * hi;
                Qw[base + (size_t)(s0 + wave * 32 + m) * 16] = f2bf(acc[r]);
            }
        } else if (nt < 4) {                // K cols 64..127
            int cc = c - 64;
            int h = cc >> 4, d = cc & 15;
            size_t base = ((size_t)(b * 4 + h) * S_LEN) * 16 + d;
            #pragma unroll
            for (int r = 0; r < 16; ++r) {
                int m = (r & 3) + 8 * (r >> 2) + 4 * hi;
                Kw[base + (size_t)(s0 + wave * 32 + m) * 16] = f2bf(acc[r]);
            }
        } else {                            // V cols 128..191 -> V^T [bh][16][S]
            int vc = c - 128;
            size_t vbase = ((size_t)(b * 4 + (vc >> 4)) * 16 + (vc & 15)) * S_LEN;
            #pragma unroll
            for (int g = 0; g < 4; ++g) {
                int m0 = 8 * g + 4 * hi;    // 4 consecutive tokens
                us4 pv = { f2bf(acc[4 * g + 0]), f2bf(acc[4 * g + 1]),
                           f2bf(acc[4 * g + 2]), f2bf(acc[4 * g + 3]) };
                *(us4*)(VTw + vbase + s0 + wave * 32 + m0) = pv;
            }
        }
    }
}

// ---------------------------------------------------------------------------
// Kernel 2: flash attention, no max-subtraction (logits bounded ~|3|).
// Block = 4 waves; each wave owns one 32-row q tile of one (b,h).
// Per 32-k tile: S = mfma_32x32x16(A=K, B=Q)  (lane: q=lane&31, k'=C-row)
//   p = exp2(S); denom += p; P -> private LDS (bf16) ; then
//   acc_{0,1} = mfma_16x16x32(A=P^T half, B=V) accumulated over k tiles.
// ---------------------------------------------------------------------------
__global__ __launch_bounds__(256) void ga_attn(
    const unsigned short* __restrict__ Qw, const unsigned short* __restrict__ Kw,
    const unsigned short* __restrict__ VTw, float* __restrict__ Ow)
{
    __shared__ __align__(16) unsigned short Pl[4][2][32][44]; // dbuf, 44-stride
    __shared__ float dnl[4][32];

    const int tid = threadIdx.x;
    const int lane = tid & 63;
    const int wave = tid >> 6;
    const int bh = blockIdx.x >> 5;                 // 0..15
    const int qt = (blockIdx.x & 31) * 4 + wave;    // 0..127
    const int qbase = qt * 32;
    const int lq = lane & 31, hi = lane >> 5;

    const size_t head = (size_t)bh * S_LEN * 16;
    const bf16x8 qf = *(const bf16x8*)(Qw + head + (size_t)(qbase + lq) * 16 + hi * 8);
    const unsigned short* kp = Kw + head + (size_t)lq * 16 + hi * 8;
    const unsigned short* vp = VTw + head + (size_t)(lane & 15) * S_LEN + (lane >> 4) * 8;
    unsigned short* pw = &Pl[wave][0][lq][4 * hi];
    const unsigned short* pr0 = &Pl[wave][0][lane & 15][(lane >> 4) * 8];
    const unsigned short* pr1 = pr0 + 16 * 44;

    const f32x16 zero16 = {};
    f32x4 acc0 = {}, acc1 = {};
    float denomA = 0.f, denomB = 0.f;

    bf16x8 kf = *(const bf16x8*)(kp);
    bf16x8 vf = *(const bf16x8*)(vp);

    for (int kt = 0; kt < 128; ++kt) {
        f32x16 sv = __builtin_amdgcn_mfma_f32_32x32x16_bf16(kf, qf, zero16, 0, 0, 0);
        bf16x8 vc = vf;
        // prefetch next tile (clamped; issued before the LDS fence)
        const int ktn = (kt + 1) & 127;
        kf = *(const bf16x8*)(kp + (size_t)ktn * 512);
        vf = *(const bf16x8*)(vp + (size_t)ktn * 32);

        const int boff = (kt & 1) * (32 * 44);
        #pragma unroll
        for (int g = 0; g < 4; ++g) {
            float p0 = fast_exp2(sv[4*g+0]);
            float p1 = fast_exp2(sv[4*g+1]);
            float p2 = fast_exp2(sv[4*g+2]);
            float p3 = fast_exp2(sv[4*g+3]);
            if (g & 1) denomB += (p0 + p1) + (p2 + p3);
            else       denomA += (p0 + p1) + (p2 + p3);
            us4 pk = { f2bf(p0), f2bf(p1), f2bf(p2), f2bf(p3) };
            *(us4*)(pw + boff + 8 * g) = pk;   // rows k' = 8g+4hi .. +3, col q=lq
        }
        asm volatile("s_waitcnt lgkmcnt(0)" ::: "memory");

        bf16x4 a0l = *(const bf16x4*)(pr0 + boff);
        bf16x4 a0h = *(const bf16x4*)(pr0 + boff + 4);
        bf16x4 a1l = *(const bf16x4*)(pr1 + boff);
        bf16x4 a1h = *(const bf16x4*)(pr1 + boff + 4);
        bf16x8 a0 = __builtin_shufflevector(a0l, a0h, 0,1,2,3,4,5,6,7);
        bf16x8 a1 = __builtin_shufflevector(a1l, a1h, 0,1,2,3,4,5,6,7);
        acc0 = __builtin_amdgcn_mfma_f32_16x16x32_bf16(a0, vc, acc0, 0, 0, 0);
        acc1 = __builtin_amdgcn_mfma_f32_16x16x32_bf16(a1, vc, acc1, 0, 0, 0);
    }

    float denom = denomA + denomB;
    denom += __shfl_xor(denom, 32);
    if (lane < 32) dnl[wave][lane] = denom;
    asm volatile("s_waitcnt lgkmcnt(0)" ::: "memory");

    const int b = bh >> 2, h = bh & 3;
    const int d = lane & 15;
    const int qr = (lane >> 4) * 4;
    float* op = Ow + ((size_t)b * S_LEN + qbase) * 64 + h * 16 + d;
    #pragma unroll
    for (int r = 0; r < 4; ++r) {
        float dn0 = dnl[wave][qr + r];
        float dn1 = dnl[wave][qr + r + 16];
        op[(size_t)(qr + r) * 64]      = acc0[r] / dn0;
        op[(size_t)(qr + r + 16) * 64] = acc1[r] / dn1;
    }
}

// ---------------------------------------------------------------------------
// Kernel 3: out = O @ Wo   (fp32, Wo staged in LDS)
// ---------------------------------------------------------------------------
__global__ __launch_bounds__(256) void ga_wo(
    const float* __restrict__ O, const float* __restrict__ Wo,
    float* __restrict__ out)
{
    __shared__ float wl[64][64];
    const int tid = threadIdx.x;
    #pragma unroll
    for (int r = 0; r < 16; ++r) {
        int idx = tid + r * 256;
        wl[idx >> 6][idx & 63] = Wo[idx];
    }
    __syncthreads();
    const int o = tid & 63;
    const int t = blockIdx.x * 4 + (tid >> 6);
    const float* orow = O + (size_t)t * 64;
    float acc = 0.f;
    #pragma unroll
    for (int c4 = 0; c4 < 16; ++c4) {
        float4 ov = *(const float4*)(orow + c4 * 4);
        acc += ov.x * wl[c4*4+0][o];
        acc += ov.y * wl[c4*4+1][o];
        acc += ov.z * wl[c4*4+2][o];
        acc += ov.w * wl[c4*4+3][o];
    }
    out[(size_t)t * 64 + o] = acc;
}

extern "C" void kernel_launch(void* const* d_in, const int* in_sizes, int n_in,
                              void* d_out, int out_size, void* d_ws, size_t ws_size,
                              hipStream_t stream) {
    const float* x    = (const float*)d_in[0];
    const float* gene = (const float*)d_in[1];
    const float* Wq   = (const float*)d_in[2];
    const float* Wk   = (const float*)d_in[3];
    const float* Wv   = (const float*)d_in[4];
    const float* Wo   = (const float*)d_in[5];

    unsigned short* Qw  = (unsigned short*)d_ws;                 // 2 MB
    unsigned short* Kw  = Qw + (1u << 20);                       // 2 MB
    unsigned short* VTw = Kw + (1u << 20);                       // 2 MB
    float* Ow = (float*)((char*)d_ws + 6u * (1u << 20));         // 4 MB

    ga_proj<<<128, 256, 0, stream>>>(x, gene, Wq, Wk, Wv, Qw, Kw, VTw);
    ga_attn<<<512, 256, 0, stream>>>(Qw, Kw, VTw, Ow);
    ga_wo<<<4096, 256, 0, stream>>>(Ow, Wo, (float*)d_out);
}

// Round 13
// 132.079 us; speedup vs baseline: 2.3972x; 1.1840x over previous
//
#include <hip/hip_runtime.h>

#define S_LEN 4096

typedef __attribute__((ext_vector_type(4)))  float f32x4;
typedef __attribute__((ext_vector_type(16))) float f32x16;
typedef __attribute__((ext_vector_type(8)))  short bf16x8;
typedef __attribute__((ext_vector_type(4)))  short bf16x4;
typedef __attribute__((ext_vector_type(4)))  unsigned short us4;
typedef __attribute__((ext_vector_type(2)))  unsigned int uint2v;

static __device__ __forceinline__ unsigned short f2bf(float f) {
    unsigned u = __float_as_uint(f);
    return (unsigned short)((u + 0x7fffu + ((u >> 16) & 1u)) >> 16);
}

static __device__ __forceinline__ float fast_exp2(float x) {
#if __has_builtin(__builtin_amdgcn_exp2f)
    return __builtin_amdgcn_exp2f(x);
#else
    return exp2f(x);
#endif
}

// pack 2 f32 -> u32 of 2 bf16 (RNE), T12 primitive (no builtin on gfx950)
static __device__ __forceinline__ unsigned cvt_pk_bf16(float lo, float hi) {
    unsigned r;
    asm("v_cvt_pk_bf16_f32 %0, %1, %2" : "=v"(r) : "v"(lo), "v"(hi));
    return r;
}

// ---------------------------------------------------------------------------
// Kernel 1: projections as one GEMM [tokens x 80] @ [80 x 192],
// W_cat = [Wq*0.25*log2e | Wk | Wv(zero-padded k=64..79)].  (r9: 316->156us,
// proj left the top-5; VGPR 256->~50, no spill.)
// ---------------------------------------------------------------------------
__global__ __launch_bounds__(256) void ga_proj(
    const float* __restrict__ x, const float* __restrict__ gene,
    const float* __restrict__ Wq, const float* __restrict__ Wk,
    const float* __restrict__ Wv,
    unsigned short* __restrict__ Qw, unsigned short* __restrict__ Kw,
    unsigned short* __restrict__ VTw)
{
    // wfrag[nt][kk][lane][j] = W_cat[kk*16 + (lane>>5)*8 + j][nt*32 + (lane&31)]
    __shared__ __align__(16) unsigned short wfrag[6][5][64][8];   // 30 KB

    const int tid = threadIdx.x;
    const int tok0 = blockIdx.x * 128;
    const int b = tok0 >> 12;          // batch (128 | 4096)
    const int s0 = tok0 & 4095;

    for (int idx = tid; idx < 80 * 64; idx += 256) {
        int k = idx >> 6, c = idx & 63;
        float w = Wq[idx] * 0.36067376022224085f;   // fold 0.25*log2(e)
        wfrag[c >> 5][k >> 4][(((k >> 3) & 1) << 5) | (c & 31)][k & 7] = f2bf(w);
    }
    for (int idx = tid; idx < 80 * 64; idx += 256) {
        int k = idx >> 6, c = idx & 63;
        int cg = c + 64;
        wfrag[cg >> 5][k >> 4][(((k >> 3) & 1) << 5) | (c & 31)][k & 7] = f2bf(Wk[idx]);
    }
    for (int idx = tid; idx < 64 * 64; idx += 256) {
        int k = idx >> 6, c = idx & 63;
        int cg = c + 128;
        wfrag[cg >> 5][k >> 4][(((k >> 3) & 1) << 5) | (c & 31)][k & 7] = f2bf(Wv[idx]);
    }
    for (int idx = tid; idx < 1024; idx += 256) {   // zero-pad V k=64..79
        int nt = 4 + (idx >> 9);
        int rest = idx & 511;
        wfrag[nt][4][rest >> 3][rest & 7] = 0;
    }
    __syncthreads();

    const int lane = tid & 63;
    const int wave = tid >> 6;
    const int lq = lane & 31, hi = lane >> 5;
    const int tok = tok0 + wave * 32 + lq;

    bf16x8 afrag[5];
    #pragma unroll
    for (int kk = 0; kk < 4; ++kk) {
        const float* p = x + (size_t)tok * 64 + kk * 16 + hi * 8;
        float4 l4 = *(const float4*)p;
        float4 h4 = *(const float4*)(p + 4);
        bf16x8 av;
        av[0] = (short)f2bf(l4.x); av[1] = (short)f2bf(l4.y);
        av[2] = (short)f2bf(l4.z); av[3] = (short)f2bf(l4.w);
        av[4] = (short)f2bf(h4.x); av[5] = (short)f2bf(h4.y);
        av[6] = (short)f2bf(h4.z); av[7] = (short)f2bf(h4.w);
        afrag[kk] = av;
    }
    {
        const float* p = gene + (size_t)tok * 16 + hi * 8;
        float4 l4 = *(const float4*)p;
        float4 h4 = *(const float4*)(p + 4);
        bf16x8 av;
        av[0] = (short)f2bf(l4.x); av[1] = (short)f2bf(l4.y);
        av[2] = (short)f2bf(l4.z); av[3] = (short)f2bf(l4.w);
        av[4] = (short)f2bf(h4.x); av[5] = (short)f2bf(h4.y);
        av[6] = (short)f2bf(h4.z); av[7] = (short)f2bf(h4.w);
        afrag[4] = av;
    }

    const f32x16 z16 = {};
    #pragma unroll
    for (int nt = 0; nt < 6; ++nt) {
        f32x16 acc = z16;
        #pragma unroll
        for (int kk = 0; kk < 5; ++kk) {
            bf16x8 bfr = *(const bf16x8*)&wfrag[nt][kk][lane][0];
            acc = __builtin_amdgcn_mfma_f32_32x32x16_bf16(afrag[kk], bfr, acc, 0, 0, 0);
        }
        const int c = nt * 32 + lq;
        if (nt < 2) {                       // Q cols 0..63
            int h = c >> 4, d = c & 15;
            size_t base = ((size_t)(b * 4 + h) * S_LEN) * 16 + d;
            #pragma unroll
            for (int r = 0; r < 16; ++r) {
                int m = (r & 3) + 8 * (r >> 2) + 4 * hi;
                Qw[base + (size_t)(s0 + wave * 32 + m) * 16] = f2bf(acc[r]);
            }
        } else if (nt < 4) {                // K cols 64..127
            int cc = c - 64;
            int h = cc >> 4, d = cc & 15;
            size_t base = ((size_t)(b * 4 + h) * S_LEN) * 16 + d;
            #pragma unroll
            for (int r = 0; r < 16; ++r) {
                int m = (r & 3) + 8 * (r >> 2) + 4 * hi;
                Kw[base + (size_t)(s0 + wave * 32 + m) * 16] = f2bf(acc[r]);
            }
        } else {                            // V cols 128..191 -> V^T [bh][16][S]
            int vc = c - 128;
            size_t vbase = ((size_t)(b * 4 + (vc >> 4)) * 16 + (vc & 15)) * S_LEN;
            #pragma unroll
            for (int g = 0; g < 4; ++g) {
                int m0 = 8 * g + 4 * hi;
                us4 pv = { f2bf(acc[4 * g + 0]), f2bf(acc[4 * g + 1]),
                           f2bf(acc[4 * g + 2]), f2bf(acc[4 * g + 3]) };
                *(us4*)(VTw + vbase + s0 + wave * 32 + m0) = pv;
            }
        }
    }
}

// ---------------------------------------------------------------------------
// Kernel 2: flash attention (no max-subtraction; logits bounded).
// r9 counters: 81us, VALUBusy 64%, Occupancy 17% (2 waves/SIMD), MfmaUtil 8%.
// r10 changes:
//  (1) k-split in-block: block = one 32-q tile; its 4 waves each do 32 of the
//      128 k-tiles, then block-reduce acc+denom in LDS. Grid 512->2048,
//      LDS ~30.5KB -> 5 blocks/CU -> 20 waves/CU (2.5x occupancy).
//  (2) P pack via v_cvt_pk_bf16_f32 (8 instrs) instead of f2bf bit-ops (~64).
// ---------------------------------------------------------------------------
__global__ __launch_bounds__(256) void ga_attn(
    const unsigned short* __restrict__ Qw, const unsigned short* __restrict__ Kw,
    const unsigned short* __restrict__ VTw, float* __restrict__ Ow)
{
    __shared__ __align__(16) unsigned short Pl[4][2][32][44]; // per-wave dbuf
    __shared__ float dnl[4][32];
    __shared__ __align__(16) float red[4][64][8];             // cross-wave acc

    const int tid = threadIdx.x;
    const int lane = tid & 63;
    const int wave = tid >> 6;                      // k-quarter owner
    const int bh = blockIdx.x >> 7;                 // 0..15
    const int qt = blockIdx.x & 127;                // 0..127
    const int qbase = qt * 32;
    const int lq = lane & 31, hi = lane >> 5;

    const size_t head = (size_t)bh * S_LEN * 16;
    const bf16x8 qf = *(const bf16x8*)(Qw + head + (size_t)(qbase + lq) * 16 + hi * 8);
    const unsigned short* kp = Kw + head + (size_t)lq * 16 + hi * 8;
    const unsigned short* vp = VTw + head + (size_t)(lane & 15) * S_LEN + (lane >> 4) * 8;
    unsigned short* pw = &Pl[wave][0][lq][4 * hi];
    const unsigned short* pr0 = &Pl[wave][0][lane & 15][(lane >> 4) * 8];
    const unsigned short* pr1 = pr0 + 16 * 44;

    const f32x16 zero16 = {};
    f32x4 acc0 = {}, acc1 = {};
    float denomA = 0.f, denomB = 0.f;

    const int kt0 = wave * 32;
    bf16x8 kf = *(const bf16x8*)(kp + (size_t)kt0 * 512);
    bf16x8 vf = *(const bf16x8*)(vp + (size_t)kt0 * 32);

    for (int i = 0; i < 32; ++i) {
        f32x16 sv = __builtin_amdgcn_mfma_f32_32x32x16_bf16(kf, qf, zero16, 0, 0, 0);
        bf16x8 vc = vf;
        // prefetch next tile (wraps within this wave's quarter; harmless reload)
        const int ktn = kt0 + ((i + 1) & 31);
        kf = *(const bf16x8*)(kp + (size_t)ktn * 512);
        vf = *(const bf16x8*)(vp + (size_t)ktn * 32);

        const int boff = (i & 1) * (32 * 44);
        #pragma unroll
        for (int g = 0; g < 4; ++g) {
            float p0 = fast_exp2(sv[4*g+0]);
            float p1 = fast_exp2(sv[4*g+1]);
            float p2 = fast_exp2(sv[4*g+2]);
            float p3 = fast_exp2(sv[4*g+3]);
            if (g & 1) denomB += (p0 + p1) + (p2 + p3);
            else       denomA += (p0 + p1) + (p2 + p3);
            uint2v pk = { cvt_pk_bf16(p0, p1), cvt_pk_bf16(p2, p3) };
            *(uint2v*)(pw + boff + 8 * g) = pk;   // rows k' = 8g+4hi..+3, col q=lq
        }
        asm volatile("s_waitcnt lgkmcnt(0)" ::: "memory");

        bf16x4 a0l = *(const bf16x4*)(pr0 + boff);
        bf16x4 a0h = *(const bf16x4*)(pr0 + boff + 4);
        bf16x4 a1l = *(const bf16x4*)(pr1 + boff);
        bf16x4 a1h = *(const bf16x4*)(pr1 + boff + 4);
        bf16x8 a0 = __builtin_shufflevector(a0l, a0h, 0,1,2,3,4,5,6,7);
        bf16x8 a1 = __builtin_shufflevector(a1l, a1h, 0,1,2,3,4,5,6,7);
        acc0 = __builtin_amdgcn_mfma_f32_16x16x32_bf16(a0, vc, acc0, 0, 0, 0);
        acc1 = __builtin_amdgcn_mfma_f32_16x16x32_bf16(a1, vc, acc1, 0, 0, 0);
    }

    // per-wave denom for q=lq (combine hi halves)
    float denom = denomA + denomB;
    denom += __shfl_xor(denom, 32);
    if (lane < 32) dnl[wave][lane] = denom;

    __syncthreads();
    *(f32x4*)&red[wave][lane][0] = acc0;
    *(f32x4*)&red[wave][lane][4] = acc1;
    __syncthreads();

    if (wave == 0) {
        f32x4 r0 = {}, r1 = {};
        #pragma unroll
        for (int w = 0; w < 4; ++w) {
            r0 += *(const f32x4*)&red[w][lane][0];
            r1 += *(const f32x4*)&red[w][lane][4];
        }
        const int b = bh >> 2, h = bh & 3;
        const int d = lane & 15;
        const int qr = (lane >> 4) * 4;
        float* op = Ow + ((size_t)b * S_LEN + qbase) * 64 + h * 16 + d;
        #pragma unroll
        for (int r = 0; r < 4; ++r) {
            float dn0 = dnl[0][qr+r] + dnl[1][qr+r] + dnl[2][qr+r] + dnl[3][qr+r];
            float dn1 = dnl[0][qr+r+16] + dnl[1][qr+r+16] + dnl[2][qr+r+16] + dnl[3][qr+r+16];
            op[(size_t)(qr + r) * 64]      = r0[r] / dn0;
            op[(size_t)(qr + r + 16) * 64] = r1[r] / dn1;
        }
    }
}

// ---------------------------------------------------------------------------
// Kernel 3: out = O @ Wo   (fp32, Wo staged in LDS)
// ---------------------------------------------------------------------------
__global__ __launch_bounds__(256) void ga_wo(
    const float* __restrict__ O, const float* __restrict__ Wo,
    float* __restrict__ out)
{
    __shared__ float wl[64][64];
    const int tid = threadIdx.x;
    #pragma unroll
    for (int r = 0; r < 16; ++r) {
        int idx = tid + r * 256;
        wl[idx >> 6][idx & 63] = Wo[idx];
    }
    __syncthreads();
    const int o = tid & 63;
    const int t = blockIdx.x * 4 + (tid >> 6);
    const float* orow = O + (size_t)t * 64;
    float acc = 0.f;
    #pragma unroll
    for (int c4 = 0; c4 < 16; ++c4) {
        float4 ov = *(const float4*)(orow + c4 * 4);
        acc += ov.x * wl[c4*4+0][o];
        acc += ov.y * wl[c4*4+1][o];
        acc += ov.z * wl[c4*4+2][o];
        acc += ov.w * wl[c4*4+3][o];
    }
    out[(size_t)t * 64 + o] = acc;
}

extern "C" void kernel_launch(void* const* d_in, const int* in_sizes, int n_in,
                              void* d_out, int out_size, void* d_ws, size_t ws_size,
                              hipStream_t stream) {
    const float* x    = (const float*)d_in[0];
    const float* gene = (const float*)d_in[1];
    const float* Wq   = (const float*)d_in[2];
    const float* Wk   = (const float*)d_in[3];
    const float* Wv   = (const float*)d_in[4];
    const float* Wo   = (const float*)d_in[5];

    unsigned short* Qw  = (unsigned short*)d_ws;                 // 2 MB
    unsigned short* Kw  = Qw + (1u << 20);                       // 2 MB
    unsigned short* VTw = Kw + (1u << 20);                       // 2 MB
    float* Ow = (float*)((char*)d_ws + 6u * (1u << 20));         // 4 MB

    ga_proj<<<128, 256, 0, stream>>>(x, gene, Wq, Wk, Wv, Qw, Kw, VTw);
    ga_attn<<<2048, 256, 0, stream>>>(Qw, Kw, VTw, Ow);
    ga_wo<<<4096, 256, 0, stream>>>(Ow, Wo, (float*)d_out);
}